// Round 3
// baseline (244.037 us; speedup 1.0000x reference)
//
#include <hip/hip_runtime.h>
#include <cstdint>

#define LRELU_ALPHA 0.2f
#define NEG_INF -9000000000000000.0f
#define L2E 1.4426950408889634f

typedef __bf16 bf16x8 __attribute__((ext_vector_type(8)));
typedef float floatx4 __attribute__((ext_vector_type(4)));
typedef unsigned int uintx4 __attribute__((ext_vector_type(4)));

constexpr int Bb = 8, Nn = 2048, Ff = 64;
constexpr int TJ = 64;             // j-tile width
constexpr int SEGW = 8;            // waves per block = in-block j-slices
constexpr int SLICE = Nn / SEGW;   // 256 j per wave
constexpr int NT = SLICE / TJ;     // 4 tiles per wave
constexpr int NROWS = Bb * Nn;     // 16384 global rows

__device__ __forceinline__ unsigned short f2bf(float f) {
    unsigned u = __builtin_bit_cast(unsigned, f);
    u = u + 0x7FFFu + ((u >> 16) & 1u);   // round-to-nearest-even
    return (unsigned short)(u >> 16);
}

__device__ __forceinline__ unsigned cvt_pk_bf16(float lo, float hi) {
    unsigned r;
    asm("v_cvt_pk_bf16_f32 %0, %1, %2" : "=v"(r) : "v"(lo), "v"(hi));
    return r;
}

// ---------------- Kernel 1: h = x@W (fp32), s1 = h.a1, s2 = h.a2, hT (bf16, transposed) ----
// grid 512, block 256 = 4 waves; wave w owns rows il = w*8 + r.
__global__ __launch_bounds__(256) void gat_prep(
    const float* __restrict__ x, const float* __restrict__ W, const float* __restrict__ a,
    unsigned short* __restrict__ hT, float* __restrict__ s1g, float* __restrict__ s2g)
{
    constexpr int STR2 = 36;                    // [f][il] stride (bank-stride 18 -> 2-way = free)
    __shared__ unsigned short hblk[64 * STR2];
    const int tid = threadIdx.x;
    const int blk = blockIdx.x;                 // 512 blocks: 64 row-blocks x 8 batches
    const int b  = blk >> 6;
    const int i0 = (blk & 63) * 32;
    const int w    = tid >> 6;
    const int lane = tid & 63;                  // lane = output feature f

    float wcol[64];
    #pragma unroll
    for (int k = 0; k < 64; ++k) wcol[k] = W[k * 64 + lane];
    const float a1 = a[lane], a2 = a[64 + lane];

    for (int r = 0; r < 8; ++r) {
        const int il = w * 8 + r;
        const int i  = i0 + il;
        const float* xrow = x + ((size_t)(b * Nn + i)) * 64;   // wave-uniform -> s_loads
        float h0 = 0.f, h1 = 0.f, h2 = 0.f, h3 = 0.f;          // 4 chains: break FMA dep latency
        #pragma unroll
        for (int k = 0; k < 64; k += 4) {
            h0 = fmaf(xrow[k],     wcol[k],     h0);
            h1 = fmaf(xrow[k + 1], wcol[k + 1], h1);
            h2 = fmaf(xrow[k + 2], wcol[k + 2], h2);
            h3 = fmaf(xrow[k + 3], wcol[k + 3], h3);
        }
        const float h = (h0 + h1) + (h2 + h3);
        float p1 = h * a1, p2 = h * a2;
        #pragma unroll
        for (int off = 32; off; off >>= 1) {
            p1 += __shfl_xor(p1, off);
            p2 += __shfl_xor(p2, off);
        }
        if (lane == 0) { s1g[b * Nn + i] = p1; s2g[b * Nn + i] = p2; }
        hblk[lane * STR2 + il] = f2bf(h);          // transpose via LDS
    }
    __syncthreads();
    {
        const int f = tid >> 2, c = (tid & 3) * 8;
        uint4 v = *reinterpret_cast<const uint4*>(&hblk[f * STR2 + c]);
        *reinterpret_cast<uint4*>(hT + ((size_t)b * 64 + f) * Nn + i0 + c) = v;
    }
}

// ---------------- Kernel 2: FULLY fused attention (no partials, no hT staging) ------------
// Block = 512 threads = 8 waves; block owns 16 rows; wave s sweeps j in [s*256, s*256+256).
// hT (256 KB/batch) and s2 are read straight from L2 — no LDS staging, no per-tile barriers.
// Per-wave online softmax + PV into C regs; ONE barrier; in-block LDS merge of the 8 j-slice
// partials; normalize + ELU -> final out. Occupancy: __launch_bounds__(512,6) => 24 waves/CU.
__global__ __launch_bounds__(512, 6) void gat_attn(
    const int* __restrict__ adj, const unsigned short* __restrict__ hT,
    const float* __restrict__ s1g, const float* __restrict__ s2g,
    float* __restrict__ out)
{
    __shared__ float O_lds[SEGW][16][65];      // [slice][row][f], pad 65 (2-way max on merge)
    __shared__ float m_lds[SEGW][16];
    __shared__ float l_lds[SEGW][16];

    const int tid  = threadIdx.x;
    const int blk  = blockIdx.x;          // 1024 blocks: 128 per batch
    const int b    = blk >> 7;
    const int i0   = (blk & 127) * 16;
    const int s    = tid >> 6;            // wave id = j-slice
    const int lane = tid & 63;
    const int fl   = lane & 15;           // A-row (i) in e-phase; B-col (f) in mfma phase
    const int q    = lane >> 4;           // quad id: k-group selector

    const int i = i0 + fl;                // this lane's score row
    const float s1v = s1g[b * Nn + i];
    const int* adj_row = adj + ((size_t)(b * Nn + i)) * Nn + s * SLICE;
    const unsigned short* hTb = hT + (size_t)b * 64 * Nn + s * SLICE;
    const float* s2b = s2g + b * Nn + s * SLICE;

    float m = NEG_INF, l = 0.f;
    floatx4 C[4] = {};                    // 4 f-tiles of 16x16 C

    for (int jt = 0; jt < NT; ++jt) {
        const int jloc = jt * TJ;

        // adj tile [16 rows][64 j]: per lane 16 ints (no prefetch — TLP hides it)
        int4 adjv[4];
        {
            const int* arow = adj_row + jloc;
            const int4* ap0 = reinterpret_cast<const int4*>(arow + q * 8);
            adjv[0] = ap0[0]; adjv[1] = ap0[1];
            const int4* ap1 = reinterpret_cast<const int4*>(arow + 32 + q * 8);
            adjv[2] = ap1[0]; adjv[3] = ap1[1];
        }

        // scores: p[tt*8+jj] for local j = jloc + tt*32 + q*8 + jj
        float p[16];
        const int* av = reinterpret_cast<const int*>(adjv);
        #pragma unroll
        for (int tt = 0; tt < 2; ++tt) {
            float s2v[8];
            *reinterpret_cast<float4*>(&s2v[0]) =
                *reinterpret_cast<const float4*>(&s2b[jloc + tt * 32 + q * 8]);
            *reinterpret_cast<float4*>(&s2v[4]) =
                *reinterpret_cast<const float4*>(&s2b[jloc + tt * 32 + q * 8 + 4]);
            #pragma unroll
            for (int jj = 0; jj < 8; ++jj) {
                float ev = s1v + s2v[jj];
                ev = fmaxf(ev, LRELU_ALPHA * ev);              // leaky_relu, alpha<1
                p[tt * 8 + jj] = (av[tt * 8 + jj] > 0) ? ev : NEG_INF;
            }
        }
        // online softmax: row max across 16 local + cross-quad
        float tmax = p[0];
        #pragma unroll
        for (int k = 1; k < 16; ++k) tmax = fmaxf(tmax, p[k]);
        tmax = fmaxf(tmax, __shfl_xor(tmax, 16));
        tmax = fmaxf(tmax, __shfl_xor(tmax, 32));
        const float m_new = fmaxf(m, tmax);

        // defer-rescale: skip C-rescale when no lane grew its max (wave-uniform branch)
        if (__any(m_new > m)) {
            const float alpha_s = exp2f((m - m_new) * L2E);    // exp(m - m_new)
            l *= alpha_s;
            float ac[4];
            #pragma unroll
            for (int r = 0; r < 4; ++r) ac[r] = __shfl(alpha_s, q * 4 + r);
            #pragma unroll
            for (int u = 0; u < 4; ++u)
                #pragma unroll
                for (int r = 0; r < 4; ++r) C[u][r] *= ac[r];
            m = m_new;
        }

        float tsum = 0.f;
        #pragma unroll
        for (int k = 0; k < 16; ++k) {
            p[k] = exp2f((p[k] - m) * L2E);                    // exp(e - m)
            tsum += p[k];
        }
        tsum += __shfl_xor(tsum, 16);
        tsum += __shfl_xor(tsum, 32);
        l += tsum;

        // pack p -> bf16 A-fragments via v_cvt_pk_bf16_f32
        uintx4 pa, pb;
        #pragma unroll
        for (int d = 0; d < 4; ++d) {
            pa[d] = cvt_pk_bf16(p[2 * d],     p[2 * d + 1]);
            pb[d] = cvt_pk_bf16(p[8 + 2 * d], p[8 + 2 * d + 1]);
        }
        const bf16x8 A0 = __builtin_bit_cast(bf16x8, pa);
        const bf16x8 A1 = __builtin_bit_cast(bf16x8, pb);

        // PV: 4 f-tiles x 2 k-steps; B-fragments straight from L2-resident hT
        __builtin_amdgcn_s_setprio(1);
        #pragma unroll
        for (int u = 0; u < 4; ++u) {
            const bf16x8 B0 = *reinterpret_cast<const bf16x8*>(
                hTb + (size_t)(u * 16 + fl) * Nn + jloc + q * 8);
            C[u] = __builtin_amdgcn_mfma_f32_16x16x32_bf16(A0, B0, C[u], 0, 0, 0);
            const bf16x8 B1 = *reinterpret_cast<const bf16x8*>(
                hTb + (size_t)(u * 16 + fl) * Nn + jloc + 32 + q * 8);
            C[u] = __builtin_amdgcn_mfma_f32_16x16x32_bf16(A1, B1, C[u], 0, 0, 0);
        }
        __builtin_amdgcn_s_setprio(0);
    }

    // ---- in-block merge of the 8 j-slice partials ----
    #pragma unroll
    for (int u = 0; u < 4; ++u)
        #pragma unroll
        for (int r = 0; r < 4; ++r)
            O_lds[s][q * 4 + r][u * 16 + fl] = C[u][r];
    if (q == 0) { m_lds[s][fl] = m; l_lds[s][fl] = l; }
    __syncthreads();

    // 1024 outputs, 512 threads -> 2 consecutive f each; coalesced float2 store
    const int row = tid >> 5;
    const int f0  = (tid & 31) * 2;

    float mv[SEGW];
    #pragma unroll
    for (int k = 0; k < SEGW; ++k) mv[k] = m_lds[k][row];
    float mstar = mv[0];
    #pragma unroll
    for (int k = 1; k < SEGW; ++k) mstar = fmaxf(mstar, mv[k]);

    float lsum = 0.f, acc0 = 0.f, acc1 = 0.f;
    #pragma unroll
    for (int k = 0; k < SEGW; ++k) {
        const float wgt = exp2f((mv[k] - mstar) * L2E);
        lsum += l_lds[k][row] * wgt;
        const float2 ov = *reinterpret_cast<const float2*>(&O_lds[k][row][f0]);
        acc0 += ov.x * wgt;
        acc1 += ov.y * wgt;
    }
    const float inv = 1.f / lsum;
    float v0 = acc0 * inv, v1 = acc1 * inv;
    v0 = (v0 > 0.f) ? v0 : (exp2f(v0 * L2E) - 1.f);    // elu, alpha=1
    v1 = (v1 > 0.f) ? v1 : (exp2f(v1 * L2E) - 1.f);
    float2 o2; o2.x = v0; o2.y = v1;
    *reinterpret_cast<float2*>(&out[((size_t)(b * Nn + i0 + row)) * 64 + f0]) = o2;
}

extern "C" void kernel_launch(void* const* d_in, const int* in_sizes, int n_in,
                              void* d_out, int out_size, void* d_ws, size_t ws_size,
                              hipStream_t stream) {
    const float* x   = (const float*)d_in[0];
    const int*   adj = (const int*)d_in[1];
    const float* W   = (const float*)d_in[2];
    const float* a   = (const float*)d_in[3];
    float* out = (float*)d_out;

    // workspace: hT bf16 [B][64][N] (2 MB) + s1,s2 fp32 [B*N] (64 KB each)
    char* p = (char*)d_ws;
    unsigned short* hT = (unsigned short*)p;  p += (size_t)Bb * 64 * Nn * sizeof(unsigned short);
    float* s1 = (float*)p;                    p += (size_t)NROWS * sizeof(float);
    float* s2 = (float*)p;

    gat_prep<<<dim3(Bb * Nn / 32), dim3(256), 0, stream>>>(x, W, a, hT, s1, s2);
    gat_attn<<<dim3(NROWS / 16), dim3(512), 0, stream>>>(adj, hT, s1, s2, out);
}